// Round 11
// baseline (56.167 us; speedup 1.0000x reference)
//
#include <hip/hip_runtime.h>
#include <hip/hip_bf16.h>

#define B 32
#define T 8192
#define H 128

typedef __attribute__((ext_vector_type(8)))  short short8_t;   // 8 bf16 = 4 VGPR
typedef __attribute__((ext_vector_type(16))) float f32x16;     // MFMA 32x32 acc

static __device__ __forceinline__ unsigned fbits(float x) { return __builtin_bit_cast(unsigned, x); }
static __device__ __forceinline__ float bfloat(unsigned u) { return __builtin_bit_cast(float, u); }

// direct global->LDS DMA, 16 B per lane. LDS dest = wave-uniform base +
// lane*16 (HW); global src is per-lane.
static __device__ __forceinline__ void gload16(const float4* g, float4* l) {
    __builtin_amdgcn_global_load_lds(
        (const __attribute__((address_space(1))) unsigned int*)g,
        (__attribute__((address_space(3))) unsigned int*)l,
        16, 0, 0);
}

// ws layout: [0,16K) u fp32 ; [16K,80K) W2 hi|lo frags bf16
#define WPK_OFF  16384

// ---------------------------------------------------------------------------
// Kernel 1 (merged prep): blocks 0..31 -> u[b][h]; blocks 32..39 -> pack W2.
// ---------------------------------------------------------------------------
__global__ void k_prep(const float* __restrict__ hidden,
                       const float* __restrict__ W_attn,
                       const float* __restrict__ b_attn,
                       float* __restrict__ u,
                       unsigned short* __restrict__ wpk) {
    const int tid = threadIdx.x;
    if (blockIdx.x < 32) {
        const int b = blockIdx.x;
        __shared__ float hrow[H];
        if (tid < H) hrow[tid] = hidden[b * H + tid];
        __syncthreads();
        if (tid < H) {
            const float* w = W_attn + (size_t)tid * (2 * H);
            float acc = b_attn[tid];
#pragma unroll
            for (int k = 0; k < H; ++k) acc = fmaf(w[k], hrow[k], acc);
            u[b * H + tid] = acc;
        }
    } else {
        const int idx  = (blockIdx.x - 32) * 256 + tid;   // 0..2047
        const int s    = idx >> 8;
        const int m    = (idx >> 6) & 3;
        const int lane = idx & 63;
        const int h    = m * 32 + (lane & 31);
        const int k0   = s * 16 + (lane >> 5) * 8;
        const float* src = W_attn + (size_t)h * (2 * H) + H + k0;
        const int base = ((s * 4 + m) * 64 + lane) * 8;
#pragma unroll
        for (int e = 0; e < 8; ++e) {
            const float x = src[e];
            const unsigned ux = fbits(x);
            const unsigned hb = ux & 0xffff0000u;         // truncated bf16 hi
            const float r = x - bfloat(hb);               // exact remainder
            wpk[base + e]         = (unsigned short)(ux >> 16);
            wpk[16384 + base + e] = (unsigned short)(fbits(r) >> 16);
        }
    }
}

// ---------------------------------------------------------------------------
// Kernel 2: scores via MFMA — T3 2-phase double-buffered global_load_lds.
//
// Round = 2 t-values (64 enc rows = 32 KB); two 32 KB LDS buffers alternate.
// Per round: ISSUE next tile's DMA first, then compute the current buffer;
// the single __syncthreads (implicit vmcnt(0)) is the drain — stage overlaps
// compute instead of serializing (r10 was stage -> drain -> compute).
//
// Wave split: tsel = wid>>2 (which t), mtile = wid&3 (which 32-row h-tile).
// acc = 1 x f32x16 = 16 regs/wave. 4-way h-combine through parity-indexed
// cbuf (parity removes the second barrier: round q reads cbuf[q&1] after
// barrier q; round q+2 rewrites it only after barrier q+1).
//
// Swizzle (rule #21, validated r9/r10): LDS linear [row][slot]; slot j of
// row r receives global unit (j-r)&31 via per-lane source addr; reader
// fetches unit d at slot (d + l31) & 31 (row mod 32 == l31).
// ---------------------------------------------------------------------------
__global__ __launch_bounds__(512, 2) void k_scores_mfma(
    const float* __restrict__ enc,                 // [T*B][H]
    const float* __restrict__ u,                   // [B][H]
    const float* __restrict__ v,                   // [H]
    const unsigned short* __restrict__ wpk,        // 64 KB frag-ordered hi|lo
    float* __restrict__ scores)                    // [B][T]
{
    __shared__ unsigned short wlds[32768];         // 64 KB W2 frags
    __shared__ float4 ebuf4[2][2048];              // 2 x 32 KB enc tiles
    __shared__ float cbuf[2][2][4][32];            // [parity][tsel][mtile][b]

    const int tid   = threadIdx.x;
    const int lane  = tid & 63;
    const int wid   = tid >> 6;     // 0..7
    const int tsel  = wid >> 2;     // 0..1 : which t of the round
    const int mtile = wid & 3;      // 0..3 : 32-row h-tile
    const int l31   = lane & 31;
    const int kh    = lane >> 5;

    const int t0 = blockIdx.x * 32;             // 16 rounds x 2 t per block
    const float4* enc4 = (const float4*)enc;    // 32 units per row

    // ---- prologue: issue tile-0 DMA first (hides under wlds/uf staging) ----
    {
        const size_t brow = (size_t)t0 * 32;
#pragma unroll
        for (int i = 0; i < 4; ++i) {
            const int rl = wid * 8 + 2 * i + kh;         // tile row 0..63
            const int gu = (l31 - rl) & 31;              // inverse rotation
            gload16(enc4 + (brow + rl) * 32 + gu,
                    &ebuf4[0][(wid * 8 + 2 * i) * 32]);
        }
    }

    // one-time stage of packed W2 frags
    {
        const float4* src = (const float4*)wpk;
        float4* dst = (float4*)wlds;
#pragma unroll
        for (int i = 0; i < 8; ++i) dst[tid + i * 512] = src[tid + i * 512];
    }

    // hoisted round-invariant u fragment (C-init) — 16 VGPRs
    float4 uf[4];
#pragma unroll
    for (int r4 = 0; r4 < 4; ++r4)
        uf[r4] = *(const float4*)(u + l31 * H + mtile * 32 + r4 * 8 + kh * 4);

    // read-side constants
    const int ebase = tsel * 1024 + l31 * 32;   // float4 index of own row
    const int roff  = 2 * kh + l31;             // rotation + kh unit offset

    __syncthreads();   // drains tile-0 DMA + wlds writes

    for (int q = 0; q < 16; ++q) {
        // ---- issue NEXT tile's DMA before computing this one (T3) ----
        if (q < 15) {
            const size_t brow = (size_t)(t0 + 2 * (q + 1)) * 32;
            float4* dst = &ebuf4[(q + 1) & 1][0];
#pragma unroll
            for (int i = 0; i < 4; ++i) {
                const int rl = wid * 8 + 2 * i + kh;
                const int gu = (l31 - rl) & 31;
                gload16(enc4 + (brow + rl) * 32 + gu,
                        dst + (wid * 8 + 2 * i) * 32);
            }
        }

        // ---- compute own (t, mtile) from current buffer ----
        const int g = t0 + 2 * q + tsel;        // t index
        const float4* ebq = &ebuf4[q & 1][0];

        f32x16 acc;
#pragma unroll
        for (int r4 = 0; r4 < 4; ++r4) {
            acc[4 * r4 + 0] = uf[r4].x; acc[4 * r4 + 1] = uf[r4].y;
            acc[4 * r4 + 2] = uf[r4].z; acc[4 * r4 + 3] = uf[r4].w;
        }

#pragma unroll
        for (int s = 0; s < 8; ++s) {
            const int ia = (4 * s + roff) & 31;
            const int ib = (4 * s + 1 + roff) & 31;
            const float4 xa = ebq[ebase + ia];
            const float4 xb = ebq[ebase + ib];
            const float xv[8] = {xa.x, xa.y, xa.z, xa.w, xb.x, xb.y, xb.z, xb.w};

            union { short8_t v8; unsigned w[4]; } bhi, blo;
#pragma unroll
            for (int p2 = 0; p2 < 4; ++p2) {
                const float x0 = xv[2 * p2], x1 = xv[2 * p2 + 1];
                const unsigned u0 = fbits(x0), u1 = fbits(x1);
                const unsigned h0 = u0 & 0xffff0000u, h1 = u1 & 0xffff0000u;
                const float r0 = x0 - bfloat(h0), r1 = x1 - bfloat(h1);
                bhi.w[p2] = (u0 >> 16) | h1;
                blo.w[p2] = (fbits(r0) >> 16) | (fbits(r1) & 0xffff0000u);
            }

            const int fo = ((s * 4 + mtile) * 64 + lane) * 8;     // ushort idx
            const short8_t ahi = *(const short8_t*)(wlds + fo);
            const short8_t alo = *(const short8_t*)(wlds + 16384 + fo);
            acc = __builtin_amdgcn_mfma_f32_32x32x16_bf16(ahi, bhi.v8, acc, 0, 0, 0);
            acc = __builtin_amdgcn_mfma_f32_32x32x16_bf16(alo, bhi.v8, acc, 0, 0, 0);
            acc = __builtin_amdgcn_mfma_f32_32x32x16_bf16(ahi, blo.v8, acc, 0, 0, 0);
        }

        // ---- epilogue: partial score over this wave's 32 h-rows ----
        float psum = 0.f;
#pragma unroll
        for (int r4 = 0; r4 < 4; ++r4) {
            const float4 vv = *(const float4*)(v + mtile * 32 + r4 * 8 + kh * 4);
            psum = fmaf(fmaxf(acc[4 * r4 + 0], 0.f), vv.x, psum);
            psum = fmaf(fmaxf(acc[4 * r4 + 1], 0.f), vv.y, psum);
            psum = fmaf(fmaxf(acc[4 * r4 + 2], 0.f), vv.z, psum);
            psum = fmaf(fmaxf(acc[4 * r4 + 3], 0.f), vv.w, psum);
        }
        psum += __shfl_xor(psum, 32);   // collapse kh halves; lanes<32 hold b

        if (lane < 32) cbuf[q & 1][tsel][mtile][l31] = psum;

        // single barrier: orders cbuf, ebuf-reads vs next DMA, and drains
        // the stage issued at the top of this round (implicit vmcnt(0))
        __syncthreads();

        if (mtile == 0 && lane < 32) {
            const float r = cbuf[q & 1][tsel][0][l31] + cbuf[q & 1][tsel][1][l31]
                          + cbuf[q & 1][tsel][2][l31] + cbuf[q & 1][tsel][3][l31];
            scores[(size_t)l31 * T + g] = r;
        }
    }
}

// ---------------------------------------------------------------------------
// Kernel 3: ragged masked softmax per b, row in registers (1R + 1W).
// ---------------------------------------------------------------------------
#define SM_TPB 1024
#define SM_PER (T / SM_TPB)

__global__ __launch_bounds__(SM_TPB) void k_softmax(
    float* __restrict__ out, const int* __restrict__ len_seq)
{
    const int b    = blockIdx.x;
    const int tid  = threadIdx.x;
    const int lane = tid & 63;
    const int wid  = tid >> 6;
    const int len  = len_seq[b];
    float* s = out + (size_t)b * T;

    __shared__ float red[16];

    float val[SM_PER];
#pragma unroll
    for (int i = 0; i < SM_PER; ++i) val[i] = s[tid + i * SM_TPB];

    float m = -1e30f;
#pragma unroll
    for (int i = 0; i < SM_PER; ++i)
        if (tid + i * SM_TPB < len) m = fmaxf(m, val[i]);
#pragma unroll
    for (int off = 32; off >= 1; off >>= 1) m = fmaxf(m, __shfl_xor(m, off));
    if (lane == 0) red[wid] = m;
    __syncthreads();
    if (wid == 0) {
        float xv = (lane < 16) ? red[lane] : -1e30f;
#pragma unroll
        for (int off = 8; off >= 1; off >>= 1) xv = fmaxf(xv, __shfl_xor(xv, off));
        if (lane == 0) red[0] = xv;
    }
    __syncthreads();
    m = red[0];
    __syncthreads();

    float sum = 0.0f;
#pragma unroll
    for (int i = 0; i < SM_PER; ++i) {
        const int t = tid + i * SM_TPB;
        val[i] = (t < len) ? __expf(val[i] - m) : 0.0f;
        sum += val[i];
    }
#pragma unroll
    for (int off = 32; off >= 1; off >>= 1) sum += __shfl_xor(sum, off);
    if (lane == 0) red[wid] = sum;
    __syncthreads();
    if (wid == 0) {
        float xv = (lane < 16) ? red[lane] : 0.f;
#pragma unroll
        for (int off = 8; off >= 1; off >>= 1) xv += __shfl_xor(xv, off);
        if (lane == 0) red[0] = xv;
    }
    __syncthreads();
    const float inv = 1.0f / red[0];

#pragma unroll
    for (int i = 0; i < SM_PER; ++i) s[tid + i * SM_TPB] = val[i] * inv;
}

// ---------------------------------------------------------------------------
extern "C" void kernel_launch(void* const* d_in, const int* in_sizes, int n_in,
                              void* d_out, int out_size, void* d_ws, size_t ws_size,
                              hipStream_t stream) {
    const float* hidden = (const float*)d_in[0];
    const float* enc    = (const float*)d_in[1];
    const int*   len    = (const int*)d_in[2];
    const float* W      = (const float*)d_in[3];
    const float* bb     = (const float*)d_in[4];
    const float* v      = (const float*)d_in[5];

    float* out  = (float*)d_out;
    float* u_ws = (float*)d_ws;                                     // 16 KB
    unsigned short* wpk = (unsigned short*)((char*)d_ws + WPK_OFF); // 64 KB

    k_prep<<<40, 256, 0, stream>>>(hidden, W, bb, u_ws, wpk);
    k_scores_mfma<<<256, 512, 0, stream>>>(enc, u_ws, v, wpk, out);
    k_softmax<<<B, SM_TPB, 0, stream>>>(out, len);
}

// Round 12
// 55.984 us; speedup vs baseline: 1.0033x; 1.0033x over previous
//
#include <hip/hip_runtime.h>
#include <hip/hip_bf16.h>

#define B 32
#define T 8192
#define H 128

typedef __attribute__((ext_vector_type(8)))  short short8_t;   // 8 bf16 = 4 VGPR
typedef __attribute__((ext_vector_type(16))) float f32x16;     // MFMA 32x32 acc

static __device__ __forceinline__ unsigned fbits(float x) { return __builtin_bit_cast(unsigned, x); }
static __device__ __forceinline__ float bfloat(unsigned u) { return __builtin_bit_cast(float, u); }

// direct global->LDS DMA, 16 B per lane. LDS dest = wave-uniform base +
// lane*16 (HW); global src is per-lane.
static __device__ __forceinline__ void gload16(const float4* g, float4* l) {
    __builtin_amdgcn_global_load_lds(
        (const __attribute__((address_space(1))) unsigned int*)g,
        (__attribute__((address_space(3))) unsigned int*)l,
        16, 0, 0);
}

// ws layout: [0,16K) u fp32 ; [16K,80K) W2 hi|lo frags bf16
#define WPK_OFF  16384

// ---------------------------------------------------------------------------
// Kernel 1 (merged prep): blocks 0..31 -> u[b][h]; blocks 32..39 -> pack W2.
// ---------------------------------------------------------------------------
__global__ void k_prep(const float* __restrict__ hidden,
                       const float* __restrict__ W_attn,
                       const float* __restrict__ b_attn,
                       float* __restrict__ u,
                       unsigned short* __restrict__ wpk) {
    const int tid = threadIdx.x;
    if (blockIdx.x < 32) {
        const int b = blockIdx.x;
        __shared__ float hrow[H];
        if (tid < H) hrow[tid] = hidden[b * H + tid];
        __syncthreads();
        if (tid < H) {
            const float* w = W_attn + (size_t)tid * (2 * H);
            float acc = b_attn[tid];
#pragma unroll
            for (int k = 0; k < H; ++k) acc = fmaf(w[k], hrow[k], acc);
            u[b * H + tid] = acc;
        }
    } else {
        const int idx  = (blockIdx.x - 32) * 256 + tid;   // 0..2047
        const int s    = idx >> 8;
        const int m    = (idx >> 6) & 3;
        const int lane = idx & 63;
        const int h    = m * 32 + (lane & 31);
        const int k0   = s * 16 + (lane >> 5) * 8;
        const float* src = W_attn + (size_t)h * (2 * H) + H + k0;
        const int base = ((s * 4 + m) * 64 + lane) * 8;
#pragma unroll
        for (int e = 0; e < 8; ++e) {
            const float x = src[e];
            const unsigned ux = fbits(x);
            const unsigned hb = ux & 0xffff0000u;         // truncated bf16 hi
            const float r = x - bfloat(hb);               // exact remainder
            wpk[base + e]         = (unsigned short)(ux >> 16);
            wpk[16384 + base + e] = (unsigned short)(fbits(r) >> 16);
        }
    }
}

// ---------------------------------------------------------------------------
// Kernel 2: scores via MFMA — W2 fragments in REGISTERS (r11 diagnosis: the
// main loop was LDS-pipe co-bound: 256 ds_read_b128/round/CU ~ 1.28 us =
// the HBM stage share; W2-in-regs removes half of those reads and frees
// 64 KB LDS for a 64 KB-per-tile double buffer -> 8 fat rounds, 8 barriers).
//
// Round = 4 t (128 rows, 64 KB), double-buffered; stage issued BEFORE
// compute (T3); barrier's implicit vmcnt(0) drains it -> steady-state round
// wall = BW leg (~2.6 us/CU). Wave = (tsel = wid>>2, mtile = wid&3),
// computes 2 t's per round; per-wave state: w2 frags 64 VGPR + uf 16 + acc
// 16 (acc per-t, sequential). 4-way mtile combine via parity cbuf (r11).
//
// Swizzle (rule #21, validated r9-r11): LDS linear [row][slot]; slot j of
// row r gets global unit (j-r)&31 via per-lane src addr; reader fetches
// unit d at slot (d + l31) & 31 (row mod 32 == l31).
// Spill watch: if WRITE balloons ~100 MB, the w2 reg arrays got demoted
// (r9 pathology) -> revert to LDS W2.
// ---------------------------------------------------------------------------
__global__ __launch_bounds__(512, 2) void k_scores_mfma(
    const float* __restrict__ enc,                 // [T*B][H]
    const float* __restrict__ u,                   // [B][H]
    const float* __restrict__ v,                   // [H]
    const unsigned short* __restrict__ wpk,        // 64 KB frag-ordered hi|lo
    float* __restrict__ scores)                    // [B][T]
{
    __shared__ float4 ebuf4[2][4096];              // 2 x 64 KB enc tiles
    __shared__ float cbuf[2][4][4][32];            // [parity][tloc][mtile][b]

    const int tid   = threadIdx.x;
    const int lane  = tid & 63;
    const int wid   = tid >> 6;     // 0..7
    const int tsel  = wid >> 2;     // 0..1 : t-pair of the round
    const int mtile = wid & 3;      // 0..3 : 32-row h-tile
    const int l31   = lane & 31;
    const int kh    = lane >> 5;

    const int t0 = blockIdx.x * 32;             // 8 rounds x 4 t per block
    const float4* enc4 = (const float4*)enc;    // 32 units per row

    // ---- prologue: issue tile-0 DMA first (hides under reg staging) ----
    {
        const size_t brow = (size_t)t0 * 32;
#pragma unroll
        for (int i = 0; i < 8; ++i) {
            const int rl = wid * 16 + 2 * i + kh;        // tile row 0..127
            const int gu = (l31 - rl) & 31;              // inverse rotation
            gload16(enc4 + (brow + rl) * 32 + gu,
                    &ebuf4[0][(wid * 16 + 2 * i) * 32]);
        }
    }

    // ---- W2 fragments for this wave's mtile -> 64 VGPRs (all 8 K-steps) ----
    short8_t w2hi[8], w2lo[8];
#pragma unroll
    for (int s = 0; s < 8; ++s) {
        const int fo = ((s * 4 + mtile) * 64 + lane) * 8;   // ushort idx
        w2hi[s] = *(const short8_t*)(wpk + fo);
        w2lo[s] = *(const short8_t*)(wpk + 16384 + fo);
    }

    // hoisted round-invariant u fragment (C-init) — 16 VGPRs
    float4 uf[4];
#pragma unroll
    for (int r4 = 0; r4 < 4; ++r4)
        uf[r4] = *(const float4*)(u + l31 * H + mtile * 32 + r4 * 8 + kh * 4);

    const int roff = 2 * kh + l31;              // rotation + kh unit offset

    __syncthreads();   // drains tile-0 DMA

    for (int q = 0; q < 8; ++q) {
        // ---- issue NEXT tile's DMA before computing this one (T3) ----
        if (q < 7) {
            const size_t brow = (size_t)(t0 + 4 * (q + 1)) * 32;
            float4* dst = &ebuf4[(q + 1) & 1][0];
#pragma unroll
            for (int i = 0; i < 8; ++i) {
                const int rl = wid * 16 + 2 * i + kh;
                const int gu = (l31 - rl) & 31;
                gload16(enc4 + (brow + rl) * 32 + gu,
                        dst + (wid * 16 + 2 * i) * 32);
            }
        }

        const float4* ebq = &ebuf4[q & 1][0];

        // ---- compute this wave's 2 t-values ----
#pragma unroll
        for (int tt = 0; tt < 2; ++tt) {
            const int tloc = 2 * tsel + tt;
            const int ebase = tloc * 1024 + l31 * 32;

            f32x16 acc;
#pragma unroll
            for (int r4 = 0; r4 < 4; ++r4) {
                acc[4 * r4 + 0] = uf[r4].x; acc[4 * r4 + 1] = uf[r4].y;
                acc[4 * r4 + 2] = uf[r4].z; acc[4 * r4 + 3] = uf[r4].w;
            }

#pragma unroll
            for (int s = 0; s < 8; ++s) {
                const int ia = (4 * s + roff) & 31;
                const int ib = (4 * s + 1 + roff) & 31;
                const float4 xa = ebq[ebase + ia];
                const float4 xb = ebq[ebase + ib];
                const float xv[8] = {xa.x, xa.y, xa.z, xa.w, xb.x, xb.y, xb.z, xb.w};

                union { short8_t v8; unsigned w[4]; } bhi, blo;
#pragma unroll
                for (int p2 = 0; p2 < 4; ++p2) {
                    const float x0 = xv[2 * p2], x1 = xv[2 * p2 + 1];
                    const unsigned u0 = fbits(x0), u1 = fbits(x1);
                    const unsigned h0 = u0 & 0xffff0000u, h1 = u1 & 0xffff0000u;
                    const float r0 = x0 - bfloat(h0), r1 = x1 - bfloat(h1);
                    bhi.w[p2] = (u0 >> 16) | h1;
                    blo.w[p2] = (fbits(r0) >> 16) | (fbits(r1) & 0xffff0000u);
                }

                acc = __builtin_amdgcn_mfma_f32_32x32x16_bf16(w2hi[s], bhi.v8, acc, 0, 0, 0);
                acc = __builtin_amdgcn_mfma_f32_32x32x16_bf16(w2lo[s], bhi.v8, acc, 0, 0, 0);
                acc = __builtin_amdgcn_mfma_f32_32x32x16_bf16(w2hi[s], blo.v8, acc, 0, 0, 0);
            }

            // ---- epilogue: partial score over this wave's 32 h-rows ----
            float psum = 0.f;
#pragma unroll
            for (int r4 = 0; r4 < 4; ++r4) {
                const float4 vv = *(const float4*)(v + mtile * 32 + r4 * 8 + kh * 4);
                psum = fmaf(fmaxf(acc[4 * r4 + 0], 0.f), vv.x, psum);
                psum = fmaf(fmaxf(acc[4 * r4 + 1], 0.f), vv.y, psum);
                psum = fmaf(fmaxf(acc[4 * r4 + 2], 0.f), vv.z, psum);
                psum = fmaf(fmaxf(acc[4 * r4 + 3], 0.f), vv.w, psum);
            }
            psum += __shfl_xor(psum, 32);   // collapse kh halves

            if (lane < 32) cbuf[q & 1][tloc][mtile][l31] = psum;
        }

        // single barrier: orders cbuf + ebuf reads vs next DMA writes, and
        // drains this round's stage (implicit vmcnt(0)) -> BW wall only
        __syncthreads();

        if (mtile == 0 && lane < 32) {
#pragma unroll
            for (int tt = 0; tt < 2; ++tt) {
                const int tloc = 2 * tsel + tt;
                const float r = cbuf[q & 1][tloc][0][l31] + cbuf[q & 1][tloc][1][l31]
                              + cbuf[q & 1][tloc][2][l31] + cbuf[q & 1][tloc][3][l31];
                scores[(size_t)l31 * T + (t0 + 4 * q + tloc)] = r;
            }
        }
    }
}

// ---------------------------------------------------------------------------
// Kernel 3: ragged masked softmax per b, row in registers (1R + 1W).
// ---------------------------------------------------------------------------
#define SM_TPB 1024
#define SM_PER (T / SM_TPB)

__global__ __launch_bounds__(SM_TPB) void k_softmax(
    float* __restrict__ out, const int* __restrict__ len_seq)
{
    const int b    = blockIdx.x;
    const int tid  = threadIdx.x;
    const int lane = tid & 63;
    const int wid  = tid >> 6;
    const int len  = len_seq[b];
    float* s = out + (size_t)b * T;

    __shared__ float red[16];

    float val[SM_PER];
#pragma unroll
    for (int i = 0; i < SM_PER; ++i) val[i] = s[tid + i * SM_TPB];

    float m = -1e30f;
#pragma unroll
    for (int i = 0; i < SM_PER; ++i)
        if (tid + i * SM_TPB < len) m = fmaxf(m, val[i]);
#pragma unroll
    for (int off = 32; off >= 1; off >>= 1) m = fmaxf(m, __shfl_xor(m, off));
    if (lane == 0) red[wid] = m;
    __syncthreads();
    if (wid == 0) {
        float xv = (lane < 16) ? red[lane] : -1e30f;
#pragma unroll
        for (int off = 8; off >= 1; off >>= 1) xv = fmaxf(xv, __shfl_xor(xv, off));
        if (lane == 0) red[0] = xv;
    }
    __syncthreads();
    m = red[0];
    __syncthreads();

    float sum = 0.0f;
#pragma unroll
    for (int i = 0; i < SM_PER; ++i) {
        const int t = tid + i * SM_TPB;
        val[i] = (t < len) ? __expf(val[i] - m) : 0.0f;
        sum += val[i];
    }
#pragma unroll
    for (int off = 32; off >= 1; off >>= 1) sum += __shfl_xor(sum, off);
    if (lane == 0) red[wid] = sum;
    __syncthreads();
    if (wid == 0) {
        float xv = (lane < 16) ? red[lane] : 0.f;
#pragma unroll
        for (int off = 8; off >= 1; off >>= 1) xv += __shfl_xor(xv, off);
        if (lane == 0) red[0] = xv;
    }
    __syncthreads();
    const float inv = 1.0f / red[0];

#pragma unroll
    for (int i = 0; i < SM_PER; ++i) s[tid + i * SM_TPB] = val[i] * inv;
}

// ---------------------------------------------------------------------------
extern "C" void kernel_launch(void* const* d_in, const int* in_sizes, int n_in,
                              void* d_out, int out_size, void* d_ws, size_t ws_size,
                              hipStream_t stream) {
    const float* hidden = (const float*)d_in[0];
    const float* enc    = (const float*)d_in[1];
    const int*   len    = (const int*)d_in[2];
    const float* W      = (const float*)d_in[3];
    const float* bb     = (const float*)d_in[4];
    const float* v      = (const float*)d_in[5];

    float* out  = (float*)d_out;
    float* u_ws = (float*)d_ws;                                     // 16 KB
    unsigned short* wpk = (unsigned short*)((char*)d_ws + WPK_OFF); // 64 KB

    k_prep<<<40, 256, 0, stream>>>(hidden, W, bb, u_ws, wpk);
    k_scores_mfma<<<256, 512, 0, stream>>>(enc, u_ws, v, wpk, out);
    k_softmax<<<B, SM_TPB, 0, stream>>>(out, len);
}

// Round 13
// 55.250 us; speedup vs baseline: 1.0166x; 1.0133x over previous
//
#include <hip/hip_runtime.h>
#include <hip/hip_bf16.h>

#define B 32
#define T 8192
#define H 128

typedef __attribute__((ext_vector_type(8)))  short short8_t;   // 8 bf16 = 4 VGPR
typedef __attribute__((ext_vector_type(16))) float f32x16;     // MFMA 32x32 acc

static __device__ __forceinline__ unsigned fbits(float x) { return __builtin_bit_cast(unsigned, x); }
static __device__ __forceinline__ float bfloat(unsigned u) { return __builtin_bit_cast(float, u); }

// direct global->LDS DMA, 16 B per lane. LDS dest = wave-uniform base +
// lane*16 (HW); global src is per-lane.
static __device__ __forceinline__ void gload16(const float4* g, float4* l) {
    __builtin_amdgcn_global_load_lds(
        (const __attribute__((address_space(1))) unsigned int*)g,
        (__attribute__((address_space(3))) unsigned int*)l,
        16, 0, 0);
}

// ws layout: [0,16K) u fp32 ; [16K,80K) W2 hi|lo frags bf16
#define WPK_OFF  16384

// ---------------------------------------------------------------------------
// Kernel 1 (merged prep): blocks 0..31 -> u[b][h]; blocks 32..39 -> pack W2.
// ---------------------------------------------------------------------------
__global__ void k_prep(const float* __restrict__ hidden,
                       const float* __restrict__ W_attn,
                       const float* __restrict__ b_attn,
                       float* __restrict__ u,
                       unsigned short* __restrict__ wpk) {
    const int tid = threadIdx.x;
    if (blockIdx.x < 32) {
        const int b = blockIdx.x;
        __shared__ float hrow[H];
        if (tid < H) hrow[tid] = hidden[b * H + tid];
        __syncthreads();
        if (tid < H) {
            const float* w = W_attn + (size_t)tid * (2 * H);
            float acc = b_attn[tid];
#pragma unroll
            for (int k = 0; k < H; ++k) acc = fmaf(w[k], hrow[k], acc);
            u[b * H + tid] = acc;
        }
    } else {
        const int idx  = (blockIdx.x - 32) * 256 + tid;   // 0..2047
        const int s    = idx >> 8;
        const int m    = (idx >> 6) & 3;
        const int lane = idx & 63;
        const int h    = m * 32 + (lane & 31);
        const int k0   = s * 16 + (lane >> 5) * 8;
        const float* src = W_attn + (size_t)h * (2 * H) + H + k0;
        const int base = ((s * 4 + m) * 64 + lane) * 8;
#pragma unroll
        for (int e = 0; e < 8; ++e) {
            const float x = src[e];
            const unsigned ux = fbits(x);
            const unsigned hb = ux & 0xffff0000u;         // truncated bf16 hi
            const float r = x - bfloat(hb);               // exact remainder
            wpk[base + e]         = (unsigned short)(ux >> 16);
            wpk[16384 + base + e] = (unsigned short)(fbits(r) >> 16);
        }
    }
}

// ---------------------------------------------------------------------------
// Kernel 2: scores via MFMA — T3+T4 counted-vmcnt pipeline (m201 recipe).
//
// r10/r11/r12 all landed 53-56 us because __syncthreads' implicit
// s_waitcnt vmcnt(0) drained the just-issued prefetch every round (serial
// in effect). This version: 3 x 32 KB buffers, 2 tiles always in flight,
// raw s_barrier + asm counted vmcnt — never drain to 0 in the main loop.
//
// Round q: [vmcnt(8): own tile-q loads landed; q+1,q+2 flying] [s_barrier:
// all waves' tile-q landed] [compute tile q] [lgkmcnt(0)+s_barrier: all
// ds_reads of buf done] [issue tile q+3 into freed buf]. Tail: vmcnt(4)@14,
// vmcnt(0)@15. NO vmem ops in loop besides DMA (scores -> LDS sbuf, stored
// in epilogue) so asm vmcnt counts stay exact. Prologue __syncthreads
// BEFORE the DMA issues drains all compiler reg-loads (clean bookkeeping).
// sched_barrier(0) fences pin LDS reads behind the waits (rule #18).
//
// Wave = (tsel = wid>>2 : t of the tile, mtile = wid&3); W2 frags in regs
// (64 VGPR, r12-proven no-spill); swizzle as r9-r12 (validated).
// ---------------------------------------------------------------------------
__global__ __launch_bounds__(512, 2) void k_scores_mfma(
    const float* __restrict__ enc,                 // [T*B][H]
    const float* __restrict__ u,                   // [B][H]
    const float* __restrict__ v,                   // [H]
    const unsigned short* __restrict__ wpk,        // 64 KB frag-ordered hi|lo
    float* __restrict__ scores)                    // [B][T]
{
    __shared__ float4 ebuf4[3][2048];              // 3 x 32 KB enc tiles
    __shared__ float cbuf[2][2][4][32];            // [parity][tsel][mtile][b]
    __shared__ float sbuf[32][32];                 // [t-local][b] results

    const int tid   = threadIdx.x;
    const int lane  = tid & 63;
    const int wid   = tid >> 6;     // 0..7
    const int tsel  = wid >> 2;     // 0..1 : which t of the tile
    const int mtile = wid & 3;      // 0..3 : 32-row h-tile
    const int l31   = lane & 31;
    const int kh    = lane >> 5;

    const int t0 = blockIdx.x * 32;             // 16 tiles x 2 t per block
    const float4* enc4 = (const float4*)enc;    // 32 units per row

    // ---- compiler reg loads: W2 frags (64 VGPR), uf, vv ----
    short8_t w2hi[8], w2lo[8];
#pragma unroll
    for (int s = 0; s < 8; ++s) {
        const int fo = ((s * 4 + mtile) * 64 + lane) * 8;   // ushort idx
        w2hi[s] = *(const short8_t*)(wpk + fo);
        w2lo[s] = *(const short8_t*)(wpk + 16384 + fo);
    }
    float4 uf[4], vv[4];
#pragma unroll
    for (int r4 = 0; r4 < 4; ++r4) {
        uf[r4] = *(const float4*)(u + l31 * H + mtile * 32 + r4 * 8 + kh * 4);
        vv[r4] = *(const float4*)(v + mtile * 32 + r4 * 8 + kh * 4);
    }

    // full drain BEFORE the pipeline starts: all compiler loads complete,
    // vmcnt = 0 for every wave -> in-loop counts are pure-DMA and exact.
    __syncthreads();

    // ---- prologue: issue tiles 0,1,2 (4 gload16 each; 12 outstanding) ----
#pragma unroll
    for (int p = 0; p < 3; ++p) {
        const size_t brow = (size_t)(t0 + 2 * p) * 32;
#pragma unroll
        for (int i = 0; i < 4; ++i) {
            const int rl = wid * 8 + 2 * i + kh;         // tile row 0..63
            const int gu = (l31 - rl) & 31;              // inverse rotation
            gload16(enc4 + (brow + rl) * 32 + gu,
                    &ebuf4[p][(wid * 8 + 2 * i) * 32]);
        }
    }
    __builtin_amdgcn_sched_barrier(0);

    const int roff = 2 * kh + l31;              // rotation + kh unit offset
    const int ebase = tsel * 1024 + l31 * 32;   // float4 index of own row
    int bsel = 0;                               // = q % 3

#pragma unroll 1
    for (int q = 0; q < 16; ++q) {
        // ---- wait: own tile-q loads landed (q+1,q+2 stay in flight) ----
        if (q < 14)       asm volatile("s_waitcnt vmcnt(8)" ::: "memory");
        else if (q == 14) asm volatile("s_waitcnt vmcnt(4)" ::: "memory");
        else              asm volatile("s_waitcnt vmcnt(0)" ::: "memory");
        __builtin_amdgcn_sched_barrier(0);
        __builtin_amdgcn_s_barrier();           // all waves: tile q landed
        __builtin_amdgcn_sched_barrier(0);

        // ---- compute own (t, mtile) from buf[bsel] ----
        const float4* ebq = &ebuf4[bsel][0];

        f32x16 acc;
#pragma unroll
        for (int r4 = 0; r4 < 4; ++r4) {
            acc[4 * r4 + 0] = uf[r4].x; acc[4 * r4 + 1] = uf[r4].y;
            acc[4 * r4 + 2] = uf[r4].z; acc[4 * r4 + 3] = uf[r4].w;
        }

#pragma unroll
        for (int s = 0; s < 8; ++s) {
            const int ia = (4 * s + roff) & 31;
            const int ib = (4 * s + 1 + roff) & 31;
            const float4 xa = ebq[ebase + ia];
            const float4 xb = ebq[ebase + ib];
            const float xv[8] = {xa.x, xa.y, xa.z, xa.w, xb.x, xb.y, xb.z, xb.w};

            union { short8_t v8; unsigned w[4]; } bhi, blo;
#pragma unroll
            for (int p2 = 0; p2 < 4; ++p2) {
                const float x0 = xv[2 * p2], x1 = xv[2 * p2 + 1];
                const unsigned u0 = fbits(x0), u1 = fbits(x1);
                const unsigned h0 = u0 & 0xffff0000u, h1 = u1 & 0xffff0000u;
                const float r0 = x0 - bfloat(h0), r1 = x1 - bfloat(h1);
                bhi.w[p2] = (u0 >> 16) | h1;
                blo.w[p2] = (fbits(r0) >> 16) | (fbits(r1) & 0xffff0000u);
            }

            acc = __builtin_amdgcn_mfma_f32_32x32x16_bf16(w2hi[s], bhi.v8, acc, 0, 0, 0);
            acc = __builtin_amdgcn_mfma_f32_32x32x16_bf16(w2lo[s], bhi.v8, acc, 0, 0, 0);
            acc = __builtin_amdgcn_mfma_f32_32x32x16_bf16(w2hi[s], blo.v8, acc, 0, 0, 0);
        }

        // ---- partial score over this wave's 32 h-rows ----
        float psum = 0.f;
#pragma unroll
        for (int r4 = 0; r4 < 4; ++r4) {
            psum = fmaf(fmaxf(acc[4 * r4 + 0], 0.f), vv[r4].x, psum);
            psum = fmaf(fmaxf(acc[4 * r4 + 1], 0.f), vv[r4].y, psum);
            psum = fmaf(fmaxf(acc[4 * r4 + 2], 0.f), vv[r4].z, psum);
            psum = fmaf(fmaxf(acc[4 * r4 + 3], 0.f), vv[r4].w, psum);
        }
        psum += __shfl_xor(psum, 32);   // collapse kh halves; lanes<32 hold b

        if (lane < 32) cbuf[q & 1][tsel][mtile][l31] = psum;

        // ---- all ds ops (ebuf reads + cbuf writes) retired, then barrier:
        //      buf[bsel] is free for reuse, cbuf visible ----
        asm volatile("s_waitcnt lgkmcnt(0)" ::: "memory");
        __builtin_amdgcn_sched_barrier(0);
        __builtin_amdgcn_s_barrier();
        __builtin_amdgcn_sched_barrier(0);

        // ---- issue tile q+3 into the freed buffer ----
        if (q < 13) {
            const size_t brow = (size_t)(t0 + 2 * (q + 3)) * 32;
            float4* dst = &ebuf4[bsel][0];
#pragma unroll
            for (int i = 0; i < 4; ++i) {
                const int rl = wid * 8 + 2 * i + kh;
                const int gu = (l31 - rl) & 31;
                gload16(enc4 + (brow + rl) * 32 + gu,
                        dst + (wid * 8 + 2 * i) * 32);
            }
        }

        // ---- combine mtile partials -> sbuf (no global store in loop) ----
        if (mtile == 0 && lane < 32) {
            const float r = cbuf[q & 1][tsel][0][l31] + cbuf[q & 1][tsel][1][l31]
                          + cbuf[q & 1][tsel][2][l31] + cbuf[q & 1][tsel][3][l31];
            sbuf[2 * q + tsel][l31] = r;
        }

        bsel = (bsel == 2) ? 0 : bsel + 1;
    }

    // ---- epilogue: coalesced score store ----
    asm volatile("s_waitcnt lgkmcnt(0)" ::: "memory");
    __builtin_amdgcn_sched_barrier(0);
    __builtin_amdgcn_s_barrier();
    {
        const int b  = tid >> 4;          // 0..31
        const int tl = (tid & 15) * 2;    // 0,2,..,30
        float2 r2 = make_float2(sbuf[tl][b], sbuf[tl + 1][b]);
        *(float2*)(scores + (size_t)b * T + t0 + tl) = r2;
    }
}

// ---------------------------------------------------------------------------
// Kernel 3: ragged masked softmax per b, row in registers (1R + 1W).
// ---------------------------------------------------------------------------
#define SM_TPB 1024
#define SM_PER (T / SM_TPB)

__global__ __launch_bounds__(SM_TPB) void k_softmax(
    float* __restrict__ out, const int* __restrict__ len_seq)
{
    const int b    = blockIdx.x;
    const int tid  = threadIdx.x;
    const int lane = tid & 63;
    const int wid  = tid >> 6;
    const int len  = len_seq[b];
    float* s = out + (size_t)b * T;

    __shared__ float red[16];

    float val[SM_PER];
#pragma unroll
    for (int i = 0; i < SM_PER; ++i) val[i] = s[tid + i * SM_TPB];

    float m = -1e30f;
#pragma unroll
    for (int i = 0; i < SM_PER; ++i)
        if (tid + i * SM_TPB < len) m = fmaxf(m, val[i]);
#pragma unroll
    for (int off = 32; off >= 1; off >>= 1) m = fmaxf(m, __shfl_xor(m, off));
    if (lane == 0) red[wid] = m;
    __syncthreads();
    if (wid == 0) {
        float xv = (lane < 16) ? red[lane] : -1e30f;
#pragma unroll
        for (int off = 8; off >= 1; off >>= 1) xv = fmaxf(xv, __shfl_xor(xv, off));
        if (lane == 0) red[0] = xv;
    }
    __syncthreads();
    m = red[0];
    __syncthreads();

    float sum = 0.0f;
#pragma unroll
    for (int i = 0; i < SM_PER; ++i) {
        const int t = tid + i * SM_TPB;
        val[i] = (t < len) ? __expf(val[i] - m) : 0.0f;
        sum += val[i];
    }
#pragma unroll
    for (int off = 32; off >= 1; off >>= 1) sum += __shfl_xor(sum, off);
    if (lane == 0) red[wid] = sum;
    __syncthreads();
    if (wid == 0) {
        float xv = (lane < 16) ? red[lane] : 0.f;
#pragma unroll
        for (int off = 8; off >= 1; off >>= 1) xv += __shfl_xor(xv, off);
        if (lane == 0) red[0] = xv;
    }
    __syncthreads();
    const float inv = 1.0f / red[0];

#pragma unroll
    for (int i = 0; i < SM_PER; ++i) s[tid + i * SM_TPB] = val[i] * inv;
}

// ---------------------------------------------------------------------------
extern "C" void kernel_launch(void* const* d_in, const int* in_sizes, int n_in,
                              void* d_out, int out_size, void* d_ws, size_t ws_size,
                              hipStream_t stream) {
    const float* hidden = (const float*)d_in[0];
    const float* enc    = (const float*)d_in[1];
    const int*   len    = (const int*)d_in[2];
    const float* W      = (const float*)d_in[3];
    const float* bb     = (const float*)d_in[4];
    const float* v      = (const float*)d_in[5];

    float* out  = (float*)d_out;
    float* u_ws = (float*)d_ws;                                     // 16 KB
    unsigned short* wpk = (unsigned short*)((char*)d_ws + WPK_OFF); // 64 KB

    k_prep<<<40, 256, 0, stream>>>(hidden, W, bb, u_ws, wpk);
    k_scores_mfma<<<256, 512, 0, stream>>>(enc, u_ws, v, wpk, out);
    k_softmax<<<B, SM_TPB, 0, stream>>>(out, len);
}

// Round 14
// 42.867 us; speedup vs baseline: 1.3103x; 1.2889x over previous
//
#include <hip/hip_runtime.h>
#include <hip/hip_bf16.h>

#define B 32
#define T 8192
#define H 128

typedef __attribute__((ext_vector_type(8)))  short short8_t;   // 8 bf16 = 4 VGPR
typedef __attribute__((ext_vector_type(16))) float f32x16;     // MFMA 32x32 acc

static __device__ __forceinline__ unsigned fbits(float x) { return __builtin_bit_cast(unsigned, x); }
static __device__ __forceinline__ float bfloat(unsigned u) { return __builtin_bit_cast(float, u); }

// split float4 -> 2 u32 of bf16-hi (truncated) + 2 u32 of bf16-lo (exact rem)
static __device__ __forceinline__ void pack4(const float4 f,
                                             unsigned& hi0, unsigned& hi1,
                                             unsigned& lo0, unsigned& lo1) {
    const unsigned u0 = fbits(f.x), u1 = fbits(f.y), u2 = fbits(f.z), u3 = fbits(f.w);
    const unsigned h0 = u0 & 0xffff0000u, h1 = u1 & 0xffff0000u;
    const unsigned h2 = u2 & 0xffff0000u, h3 = u3 & 0xffff0000u;
    const float r0 = f.x - bfloat(h0), r1 = f.y - bfloat(h1);
    const float r2 = f.z - bfloat(h2), r3 = f.w - bfloat(h3);
    hi0 = (u0 >> 16) | h1;                      hi1 = (u2 >> 16) | h3;
    lo0 = (fbits(r0) >> 16) | (fbits(r1) & 0xffff0000u);
    lo1 = (fbits(r2) >> 16) | (fbits(r3) & 0xffff0000u);
}

// ws layout: [0,16K) u fp32 ; [16K,80K) W2 hi|lo frags bf16
#define WPK_OFF  16384

// ---------------------------------------------------------------------------
// Kernel 1 (merged prep): blocks 0..31 -> u[b][h]; blocks 32..39 -> pack W2.
// ---------------------------------------------------------------------------
__global__ void k_prep(const float* __restrict__ hidden,
                       const float* __restrict__ W_attn,
                       const float* __restrict__ b_attn,
                       float* __restrict__ u,
                       unsigned short* __restrict__ wpk) {
    const int tid = threadIdx.x;
    if (blockIdx.x < 32) {
        const int b = blockIdx.x;
        __shared__ float hrow[H];
        if (tid < H) hrow[tid] = hidden[b * H + tid];
        __syncthreads();
        if (tid < H) {
            const float* w = W_attn + (size_t)tid * (2 * H);
            float acc = b_attn[tid];
#pragma unroll
            for (int k = 0; k < H; ++k) acc = fmaf(w[k], hrow[k], acc);
            u[b * H + tid] = acc;
        }
    } else {
        const int idx  = (blockIdx.x - 32) * 256 + tid;   // 0..2047
        const int s    = idx >> 8;
        const int m    = (idx >> 6) & 3;
        const int lane = idx & 63;
        const int h    = m * 32 + (lane & 31);
        const int k0   = s * 16 + (lane >> 5) * 8;
        const float* src = W_attn + (size_t)h * (2 * H) + H + k0;
        const int base = ((s * 4 + m) * 64 + lane) * 8;
#pragma unroll
        for (int e = 0; e < 8; ++e) {
            const float x = src[e];
            const unsigned ux = fbits(x);
            const unsigned hb = ux & 0xffff0000u;         // truncated bf16 hi
            const float r = x - bfloat(hb);               // exact remainder
            wpk[base + e]         = (unsigned short)(ux >> 16);
            wpk[16384 + base + e] = (unsigned short)(fbits(r) >> 16);
        }
    }
}

// ---------------------------------------------------------------------------
// Kernel 2: scores via MFMA — enc PRE-PACKED to bf16 hi/lo AT STAGE TIME.
//
// r10-r13 (4 transport variants) all ~53-56 us: transport was not the wall.
// The invariant was the hot loop: ds_read -> ~36-VALU hi/lo pack -> MFMA,
// with the pack done 4x redundantly (per mtile-wave) and only 2 waves/SIMD
// to hide the chain. This version packs each element ONCE during staging
// (threads: coalesced float4 load -> pack4 -> ds_write_b64 to hi/lo planes);
// the hot loop is now 2 ds_read_b128 + 3 MFMA per s-step, zero pack VALU.
//
// LDS planes (per parity): hi[64 rows][16 units of 16B], lo same; unit u of
// row r stored at slot (u+r)&15 (rotation; writer and reader agree).
// Reader (B-frag, lane l): row = tsel*32+l31, unit = 2s+kh -> one b128.
//
// Transport: simple T14 reg-stage. Round q: pack+write stg (tile q+1) ->
// buf[nxt]; issue loads tile q+2 -> stg (latency hides under compute);
// compute buf[cur]; one __syncthreads. stg = 16 VGPR only; total ~160 regs
// at launch_bounds(512,2) -> no spill expected (WRITE is the tripwire).
// Numerics identical to r7-r13 (same truncation split, same MFMA order).
// ---------------------------------------------------------------------------
__global__ __launch_bounds__(512, 2) void k_scores_mfma(
    const float* __restrict__ enc,                 // [T*B][H]
    const float* __restrict__ u,                   // [B][H]
    const float* __restrict__ v,                   // [H]
    const unsigned short* __restrict__ wpk,        // 64 KB frag-ordered hi|lo
    float* __restrict__ scores)                    // [B][T]
{
    __shared__ uint2 hb[2][2048];                  // hi planes, 2 x 16 KB
    __shared__ uint2 lb[2][2048];                  // lo planes, 2 x 16 KB
    __shared__ float cbuf[2][2][4][32];            // [parity][tsel][mtile][b]

    const int tid   = threadIdx.x;
    const int lane  = tid & 63;
    const int wid   = tid >> 6;     // 0..7
    const int tsel  = wid >> 2;     // 0..1 : which t of the tile
    const int mtile = wid & 3;      // 0..3 : 32-row h-tile
    const int l31   = lane & 31;
    const int kh    = lane >> 5;

    // staging role: 8 threads per tile-row, 4 float4 each
    const int srow = tid >> 3;      // tile row 0..63
    const int st8  = tid & 7;

    const int t0 = blockIdx.x * 32;             // 16 tiles x 2 t per block
    const float4* enc4 = (const float4*)enc;    // 32 x 16B units per row

    // ---- W2 fragments for this wave's mtile -> 64 VGPRs ----
    short8_t w2hi[8], w2lo[8];
#pragma unroll
    for (int s = 0; s < 8; ++s) {
        const int fo = ((s * 4 + mtile) * 64 + lane) * 8;   // ushort idx
        w2hi[s] = *(const short8_t*)(wpk + fo);
        w2lo[s] = *(const short8_t*)(wpk + 16384 + fo);
    }
    float4 uf[4], vv[4];
#pragma unroll
    for (int r4 = 0; r4 < 4; ++r4) {
        uf[r4] = *(const float4*)(u + l31 * H + mtile * 32 + r4 * 8 + kh * 4);
        vv[r4] = *(const float4*)(v + mtile * 32 + r4 * 8 + kh * 4);
    }

    // ---- prologue: tile 0 -> buf0; issue tile-1 loads ----
    float4 stg[4];
    {
        const float4* gs = enc4 + ((size_t)(t0 + 0) * 32 + srow) * 32;
#pragma unroll
        for (int i = 0; i < 4; ++i) stg[i] = gs[st8 + 8 * i];
#pragma unroll
        for (int i = 0; i < 4; ++i) {
            unsigned hi0, hi1, lo0, lo1;
            pack4(stg[i], hi0, hi1, lo0, lo1);
            const int p16 = st8 + 8 * i;
            const int idx = srow * 32 + (((p16 >> 1) + srow) & 15) * 2 + (p16 & 1);
            hb[0][idx] = make_uint2(hi0, hi1);
            lb[0][idx] = make_uint2(lo0, lo1);
        }
        const float4* gs1 = enc4 + ((size_t)(t0 + 2) * 32 + srow) * 32;
#pragma unroll
        for (int i = 0; i < 4; ++i) stg[i] = gs1[st8 + 8 * i];
    }
    __syncthreads();   // buf0 ready

    const int rrow  = tsel * 32 + l31;          // reader's tile row
    const int rbase = rrow * 32;                // uint2 base of that row

#pragma unroll 1
    for (int q = 0; q < 16; ++q) {
        const int cur = q & 1, nxt = cur ^ 1;

        // ---- pack+write tile q+1 (in stg) into buf[nxt] ----
        if (q < 15) {
#pragma unroll
            for (int i = 0; i < 4; ++i) {
                unsigned hi0, hi1, lo0, lo1;
                pack4(stg[i], hi0, hi1, lo0, lo1);
                const int p16 = st8 + 8 * i;
                const int idx = srow * 32 + (((p16 >> 1) + srow) & 15) * 2 + (p16 & 1);
                hb[nxt][idx] = make_uint2(hi0, hi1);
                lb[nxt][idx] = make_uint2(lo0, lo1);
            }
        }
        // ---- issue tile q+2 loads (latency hides under compute) ----
        if (q < 14) {
            const float4* gs = enc4 + ((size_t)(t0 + 2 * (q + 2)) * 32 + srow) * 32;
#pragma unroll
            for (int i = 0; i < 4; ++i) stg[i] = gs[st8 + 8 * i];
        }

        // ---- compute own (t, mtile) from buf[cur]: 2 ds_read + 3 MFMA /s ----
        f32x16 acc;
#pragma unroll
        for (int r4 = 0; r4 < 4; ++r4) {
            acc[4 * r4 + 0] = uf[r4].x; acc[4 * r4 + 1] = uf[r4].y;
            acc[4 * r4 + 2] = uf[r4].z; acc[4 * r4 + 3] = uf[r4].w;
        }

#pragma unroll
        for (int s = 0; s < 8; ++s) {
            const int slot = (2 * s + kh + l31) & 15;       // (unit+row)&15
            const short8_t bh = *(const short8_t*)&hb[cur][rbase + slot * 2];
            const short8_t bl = *(const short8_t*)&lb[cur][rbase + slot * 2];
            acc = __builtin_amdgcn_mfma_f32_32x32x16_bf16(w2hi[s], bh, acc, 0, 0, 0);
            acc = __builtin_amdgcn_mfma_f32_32x32x16_bf16(w2lo[s], bh, acc, 0, 0, 0);
            acc = __builtin_amdgcn_mfma_f32_32x32x16_bf16(w2hi[s], bl, acc, 0, 0, 0);
        }

        // ---- partial score over this wave's 32 h-rows ----
        float psum = 0.f;
#pragma unroll
        for (int r4 = 0; r4 < 4; ++r4) {
            psum = fmaf(fmaxf(acc[4 * r4 + 0], 0.f), vv[r4].x, psum);
            psum = fmaf(fmaxf(acc[4 * r4 + 1], 0.f), vv[r4].y, psum);
            psum = fmaf(fmaxf(acc[4 * r4 + 2], 0.f), vv[r4].z, psum);
            psum = fmaf(fmaxf(acc[4 * r4 + 3], 0.f), vv[r4].w, psum);
        }
        psum += __shfl_xor(psum, 32);   // collapse kh halves; lanes<32 hold b

        if (lane < 32) cbuf[cur][tsel][mtile][l31] = psum;

        __syncthreads();   // buf[nxt] written, cbuf[cur] visible, buf[cur] free

        if (mtile == 0 && lane < 32) {
            const float r = cbuf[cur][tsel][0][l31] + cbuf[cur][tsel][1][l31]
                          + cbuf[cur][tsel][2][l31] + cbuf[cur][tsel][3][l31];
            scores[(size_t)l31 * T + (t0 + 2 * q + tsel)] = r;
        }
    }
}

// ---------------------------------------------------------------------------
// Kernel 3: ragged masked softmax per b, row in registers (1R + 1W).
// ---------------------------------------------------------------------------
#define SM_TPB 1024
#define SM_PER (T / SM_TPB)

__global__ __launch_bounds__(SM_TPB) void k_softmax(
    float* __restrict__ out, const int* __restrict__ len_seq)
{
    const int b    = blockIdx.x;
    const int tid  = threadIdx.x;
    const int lane = tid & 63;
    const int wid  = tid >> 6;
    const int len  = len_seq[b];
    float* s = out + (size_t)b * T;

    __shared__ float red[16];

    float val[SM_PER];
#pragma unroll
    for (int i = 0; i < SM_PER; ++i) val[i] = s[tid + i * SM_TPB];

    float m = -1e30f;
#pragma unroll
    for (int i = 0; i < SM_PER; ++i)
        if (tid + i * SM_TPB < len) m = fmaxf(m, val[i]);
#pragma unroll
    for (int off = 32; off >= 1; off >>= 1) m = fmaxf(m, __shfl_xor(m, off));
    if (lane == 0) red[wid] = m;
    __syncthreads();
    if (wid == 0) {
        float xv = (lane < 16) ? red[lane] : -1e30f;
#pragma unroll
        for (int off = 8; off >= 1; off >>= 1) xv = fmaxf(xv, __shfl_xor(xv, off));
        if (lane == 0) red[0] = xv;
    }
    __syncthreads();
    m = red[0];
    __syncthreads();

    float sum = 0.0f;
#pragma unroll
    for (int i = 0; i < SM_PER; ++i) {
        const int t = tid + i * SM_TPB;
        val[i] = (t < len) ? __expf(val[i] - m) : 0.0f;
        sum += val[i];
    }
#pragma unroll
    for (int off = 32; off >= 1; off >>= 1) sum += __shfl_xor(sum, off);
    if (lane == 0) red[wid] = sum;
    __syncthreads();
    if (wid == 0) {
        float xv = (lane < 16) ? red[lane] : 0.f;
#pragma unroll
        for (int off = 8; off >= 1; off >>= 1) xv += __shfl_xor(xv, off);
        if (lane == 0) red[0] = xv;
    }
    __syncthreads();
    const float inv = 1.0f / red[0];

#pragma unroll
    for (int i = 0; i < SM_PER; ++i) s[tid + i * SM_TPB] = val[i] * inv;
}

// ---------------------------------------------------------------------------
extern "C" void kernel_launch(void* const* d_in, const int* in_sizes, int n_in,
                              void* d_out, int out_size, void* d_ws, size_t ws_size,
                              hipStream_t stream) {
    const float* hidden = (const float*)d_in[0];
    const float* enc    = (const float*)d_in[1];
    const int*   len    = (const int*)d_in[2];
    const float* W      = (const float*)d_in[3];
    const float* bb     = (const float*)d_in[4];
    const float* v      = (const float*)d_in[5];

    float* out  = (float*)d_out;
    float* u_ws = (float*)d_ws;                                     // 16 KB
    unsigned short* wpk = (unsigned short*)((char*)d_ws + WPK_OFF); // 64 KB

    k_prep<<<40, 256, 0, stream>>>(hidden, W, bb, u_ws, wpk);
    k_scores_mfma<<<256, 512, 0, stream>>>(enc, u_ws, v, wpk, out);
    k_softmax<<<B, SM_TPB, 0, stream>>>(out, len);
}